// Round 11
// baseline (102.843 us; speedup 1.0000x reference)
//
#include <hip/hip_runtime.h>
#include <hip/hip_bf16.h>

#define NXX 256
#define NG 32768
#define WID 128

typedef short bf16x8 __attribute__((ext_vector_type(8)));
typedef float f32x4 __attribute__((ext_vector_type(4)));
typedef unsigned int u32x4 __attribute__((ext_vector_type(4)));

__device__ __forceinline__ unsigned short rne_bf16(float x) {
    unsigned int u = __float_as_uint(x);
    return (unsigned short)((u + 0x7fffu + ((u >> 16) & 1u)) >> 16);
}

// ---------------------------------------------------------------------------
// Prep (r7-verified): pack Wg into A-operand fragment streams with the k-axis
// PRE-PERMUTED by pi: k=(kc:2|g:2|j2:1|j10:2) -> ch=(kc:2|j2:1|g:2|j10:2).
// GEMM is invariant under a common k-permutation of W and x, and pi makes the
// next layer's B-fragment equal to the thread's own D registers (no X LDS).
// Lane lv elem j of stream e=(l*4+kc)*8+nt holds W[pi(...)][16nt+(lv&15)].
// ---------------------------------------------------------------------------
__global__ __launch_bounds__(64) void prep_kernel(
    const float* __restrict__ Wg, unsigned short* __restrict__ Bfrag) {
    const int e  = blockIdx.x;       // 0..127
    const int lv = threadIdx.x;      // 0..63
    const int l  = e >> 5;
    const int kc = (e >> 3) & 3;
    const int nt = e & 7;
    const int n  = nt * 16 + (lv & 15);
    const int g  = lv >> 4;          // k-granule 0..3
#pragma unroll
    for (int j = 0; j < 8; ++j) {
        const int ch = kc * 32 + ((j >> 2) << 4) + (g << 2) + (j & 3);  // pi
        float v = Wg[(size_t)l * 16384 + (size_t)ch * WID + n];
        Bfrag[(size_t)e * 512 + lv * 8 + j] = rne_bf16(v);
    }
}

__device__ __forceinline__ unsigned int pack_bf2(float a, float b) {
    union { __hip_bfloat162 h2; unsigned int u; } cv;
    cv.h2 = __float22bfloat162_rn(make_float2(a, b));   // low16 = a
    return cv.u;
}

union fragu { bf16x8 f; u32x4 u; };

// ---------------------------------------------------------------------------
// Fused net (r9 node/batch structure). Each wave owns 16 nodes u and computes
// TWO tiles/layer (batch b, b+2) -> pair-mix register-local (no shuffles).
// r11 change: W tiles live in LDS (2 x 32KB double-buffer, reg-staged with
// issue-early/write-late, ONE barrier per layer); X-fragments come straight
// from the thread's own D registers via the pi-permutation (no X LDS, no L2
// loads in the MFMA loop). MFMA = ds_read_b128 (linear, conflict-free,
// lgkmcnt-pipelined) x register operand.
// ---------------------------------------------------------------------------
__global__ __launch_bounds__(256) void fused_kernel(
    const float* __restrict__ u0, const float* __restrict__ P,
    const float* __restrict__ W_in, const float* __restrict__ b_in,
    const unsigned short* __restrict__ Bfrag,
    const float* __restrict__ bg, const float* __restrict__ gamma,
    const float* __restrict__ beta, const float* __restrict__ W_out,
    const float* __restrict__ b_out, float* __restrict__ out)
{
    __shared__ unsigned short Wlds[2 * 16384];   // 64 KB, two 32 KB layer bufs

    const int tid  = threadIdx.x;
    const int w    = tid >> 6;
    const int lane = tid & 63;
    const int l15  = lane & 15;
    const int lhi  = lane >> 4;      // 0..3

    const int blk  = blockIdx.x;     // 0..1023
    const int b    = blk >> 9;       // 0 or 1; partner batch = b+2
    const int ublk = (blk & 511) << 6;

    const int u  = ublk + 16 * w + l15;
    const int ix = u >> 7;
    const int t  = u & 127;

    // ---- prologue: issue layer-0 W staging loads FIRST (hide under X0) ----
    const uint4* gW = (const uint4*)Bfrag;      // 2048 uint4 per layer
    uint4 stg[8];
#pragma unroll
    for (int it = 0; it < 8; ++it) stg[it] = gW[tid + it * 256];

    // degree coeffs (t-major graph indexing), per-lane
    float c1, c2;
    {
        int gi = u & 255, gt = u >> 8;
        int d  = (gi > 0) + (gi < 255) + (gt > 0) + (gt < 127);
        float deg = 2.f * (float)d + 1.f;
        c1 = 2.f * (float)d * rsqrtf(deg);
        c2 = 1.f / deg;
    }

    // ---- features of node u for batch b (A) and b+2 (B) ----
    float featA[7], featB[7];
    {
        float s  = ((float)t + 0.5f) * 0.125f - 0.5f;
        float fs = floorf(s);
        int   t0 = (int)fs;
        float wt = s - fs;
        int t0c = t0 < 0 ? 0 : (t0 > 15 ? 15 : t0);
        int t1n = t0 + 1;
        int t1c = t1n < 0 ? 0 : (t1n > 15 ? 15 : t1n);
        const float* urA = u0 + ((size_t)b * NXX + ix) * 16;
        const float* urB = u0 + ((size_t)(b + 2) * NXX + ix) * 16;
        featA[0] = urA[t0c] * (1.f - wt) + urA[t1c] * wt;
        featB[0] = urB[t0c] * (1.f - wt) + urB[t1c] * wt;
#pragma unroll
        for (int f = 0; f < 4; ++f) {
            featA[1 + f] = P[b * 4 + f];
            featB[1 + f] = P[(b + 2) * 4 + f];
        }
        featA[5] = featB[5] = (float)ix * (1.f / 255.f);
        featA[6] = featB[6] = (float)t  * (1.f / 127.f);
    }

    // ---- X0 = feat @ W_in + b_in for both tiles (D-layout) ----
    float xr0[8][4], xr1[8][4];
#pragma unroll
    for (int nt = 0; nt < 8; ++nt) {
        const int c = nt * 16 + 4 * lhi;
        float4 bi4 = *(const float4*)(b_in + c);
        float4 wf[7];
#pragma unroll
        for (int f = 0; f < 7; ++f) wf[f] = *(const float4*)(W_in + f * WID + c);
#pragma unroll
        for (int r = 0; r < 4; ++r) {
            float a0 = ((const float*)&bi4)[r];
            float a1 = a0;
#pragma unroll
            for (int f = 0; f < 7; ++f) {
                float wv = ((const float*)&wf[f])[r];
                a0 = fmaf(featA[f], wv, a0);
                a1 = fmaf(featB[f], wv, a1);
            }
            xr0[nt][r] = a0;
            xr1[nt][r] = a1;
        }
    }

    // ---- write layer-0 staging, barrier ----
    {
        char* swr = (char*)Wlds + tid * 16;
#pragma unroll
        for (int it = 0; it < 8; ++it)
            *(uint4*)(swr + it * 4096) = stg[it];
    }
    __syncthreads();

    const char* wbase = (const char*)Wlds + lane * 16;

    // ======== 4 GCN layers ========
    for (int l = 0; l < 4; ++l) {
        const int cur = (l & 1) << 15;   // byte offset of current buffer

        // ---- issue next-layer staging loads EARLY (latency hides in MFMA) --
        if (l < 3) {
#pragma unroll
            for (int it = 0; it < 8; ++it)
                stg[it] = gW[(l + 1) * 2048 + tid + it * 256];
        }

        // ---- pack B-fragments straight from xres registers (pi layout) ----
        fragu xh0[4], xh1[4];
#pragma unroll
        for (int kc = 0; kc < 4; ++kc) {
            xh0[kc].u = (u32x4){pack_bf2(xr0[2 * kc][0],     xr0[2 * kc][1]),
                                pack_bf2(xr0[2 * kc][2],     xr0[2 * kc][3]),
                                pack_bf2(xr0[2 * kc + 1][0], xr0[2 * kc + 1][1]),
                                pack_bf2(xr0[2 * kc + 1][2], xr0[2 * kc + 1][3])};
            xh1[kc].u = (u32x4){pack_bf2(xr1[2 * kc][0],     xr1[2 * kc][1]),
                                pack_bf2(xr1[2 * kc][2],     xr1[2 * kc][3]),
                                pack_bf2(xr1[2 * kc + 1][0], xr1[2 * kc + 1][1]),
                                pack_bf2(xr1[2 * kc + 1][2], xr1[2 * kc + 1][3])};
        }

        // ---- MFMA both tiles: A = W^T tile from LDS, B = registers ----
        f32x4 acc0[8], acc1[8];
#pragma unroll
        for (int nt = 0; nt < 8; ++nt) {
            f32x4 a0 = {0.f, 0.f, 0.f, 0.f};
            f32x4 a1 = {0.f, 0.f, 0.f, 0.f};
#pragma unroll
            for (int kc = 0; kc < 4; ++kc) {
                bf16x8 bh = *(const bf16x8*)(wbase + cur + (kc * 8 + nt) * 1024);
                a0 = __builtin_amdgcn_mfma_f32_16x16x32_bf16(bh, xh0[kc].f, a0, 0, 0, 0);
                a1 = __builtin_amdgcn_mfma_f32_16x16x32_bf16(bh, xh1[kc].f, a1, 0, 0, 0);
            }
            acc0[nt] = a0;
            acc1[nt] = a1;
        }

        // ---- epilogue: register-local pair mix, +bg, LN, residual ReLU ----
        float s0 = 0.f, q0 = 0.f, s1 = 0.f, q1 = 0.f;
#pragma unroll
        for (int nt = 0; nt < 8; ++nt) {
            float4 bg4 = *(const float4*)(bg + l * WID + nt * 16 + 4 * lhi);
#pragma unroll
            for (int r = 0; r < 4; ++r) {
                float bgr = ((const float*)&bg4)[r];
                float h0 = acc0[nt][r];
                float h1 = acc1[nt][r];
                float a0 = h0 + bgr;                          // batch b (deg 1)
                float a1 = fmaf(c1, h0, fmaf(c2, h1, bgr));   // batch b+2
                acc0[nt][r] = a0;
                acc1[nt][r] = a1;
                s0 += a0;  q0 = fmaf(a0, a0, q0);
                s1 += a1;  q1 = fmaf(a1, a1, q1);
            }
        }
        s0 += __shfl_xor(s0, 16);  q0 += __shfl_xor(q0, 16);
        s1 += __shfl_xor(s1, 16);  q1 += __shfl_xor(q1, 16);
        s0 += __shfl_xor(s0, 32);  q0 += __shfl_xor(q0, 32);
        s1 += __shfl_xor(s1, 32);  q1 += __shfl_xor(q1, 32);
        float mu0 = s0 * (1.f / 128.f);
        float mu1 = s1 * (1.f / 128.f);
        float rs0 = rsqrtf(q0 * (1.f / 128.f) - mu0 * mu0 + 1e-5f);
        float rs1 = rsqrtf(q1 * (1.f / 128.f) - mu1 * mu1 + 1e-5f);
#pragma unroll
        for (int nt = 0; nt < 8; ++nt) {
            const int c = nt * 16 + 4 * lhi;
            float4 g4 = *(const float4*)(gamma + l * WID + c);
            float4 e4 = *(const float4*)(beta  + l * WID + c);
#pragma unroll
            for (int r = 0; r < 4; ++r) {
                float gv = ((const float*)&g4)[r];
                float ev = ((const float*)&e4)[r];
                float n0 = fmaf((acc0[nt][r] - mu0) * rs0, gv, ev);
                float n1 = fmaf((acc1[nt][r] - mu1) * rs1, gv, ev);
                xr0[nt][r] = fmaxf(n0 + xr0[nt][r], 0.f);
                xr1[nt][r] = fmaxf(n1 + xr1[nt][r], 0.f);
            }
        }

        // ---- write next layer's W into the other buffer, one barrier ----
        if (l < 3) {
            const int nxt = ((l + 1) & 1) << 15;
            char* swr = (char*)Wlds + nxt + tid * 16;
#pragma unroll
            for (int it = 0; it < 8; ++it)
                *(uint4*)(swr + it * 4096) = stg[it];
            __syncthreads();
        }
    }

    // ======== out head: two rows per lane ========
    float p0 = 0.f, p1 = 0.f;
#pragma unroll
    for (int nt = 0; nt < 8; ++nt) {
        float4 wo4 = *(const float4*)(W_out + nt * 16 + 4 * lhi);
#pragma unroll
        for (int r = 0; r < 4; ++r) {
            float wv = ((const float*)&wo4)[r];
            p0 = fmaf(xr0[nt][r], wv, p0);
            p1 = fmaf(xr1[nt][r], wv, p1);
        }
    }
    p0 += __shfl_xor(p0, 16);  p1 += __shfl_xor(p1, 16);
    p0 += __shfl_xor(p0, 32);  p1 += __shfl_xor(p1, 32);
    if (lhi == 0) {
        float bo = b_out[0];
        out[(size_t)b * NG + u]       = p0 + bo;
        out[(size_t)(b + 2) * NG + u] = p1 + bo;
    }
}

// ---------------------------------------------------------------------------
extern "C" void kernel_launch(void* const* d_in, const int* in_sizes, int n_in,
                              void* d_out, int out_size, void* d_ws, size_t ws_size,
                              hipStream_t stream) {
    const float* u0    = (const float*)d_in[0];
    const float* P     = (const float*)d_in[1];
    const float* W_in  = (const float*)d_in[2];
    const float* b_in  = (const float*)d_in[3];
    const float* Wg    = (const float*)d_in[4];
    const float* bg    = (const float*)d_in[5];
    const float* gamma = (const float*)d_in[6];
    const float* beta  = (const float*)d_in[7];
    const float* W_out = (const float*)d_in[8];
    const float* b_out = (const float*)d_in[9];

    unsigned short* Bfrag = (unsigned short*)d_ws;   // 128 KB

    prep_kernel<<<128, 64, 0, stream>>>(Wg, Bfrag);
    fused_kernel<<<1024, 256, 0, stream>>>(
        u0, P, W_in, b_in, Bfrag, bg, gamma, beta, W_out, b_out, (float*)d_out);
}

// Round 12
// 62.402 us; speedup vs baseline: 1.6481x; 1.6481x over previous
//
#include <hip/hip_runtime.h>
#include <hip/hip_bf16.h>

#define NXX 256
#define NG 32768
#define WID 128
#define STRW 68   // LDS row stride in u32 words (odd*4: aligned b128, spread banks)

typedef short bf16x8 __attribute__((ext_vector_type(8)));
typedef float f32x4 __attribute__((ext_vector_type(4)));

__device__ __forceinline__ unsigned short rne_bf16(float x) {
    unsigned int u = __float_as_uint(x);
    return (unsigned short)((u + 0x7fffu + ((u >> 16) & 1u)) >> 16);
}

// ---------------------------------------------------------------------------
// Prep: pack Wg (4 layers of [128 k][128 n] fp32) into fragment-linear bf16
// streams. Lane l of stream e=(l*4+kc)*8+nt holds W[kc*32+(l>>4)*8+j][nt*16+(l&15)].
// Used as the *A* operand of mfma (W^T tile).
// ---------------------------------------------------------------------------
__global__ __launch_bounds__(64) void prep_kernel(
    const float* __restrict__ Wg, unsigned short* __restrict__ Bfrag) {
    const int e  = blockIdx.x;       // 0..127
    const int lv = threadIdx.x;      // 0..63
    const int l  = e >> 5;
    const int kc = (e >> 3) & 3;
    const int nt = e & 7;
    const int n  = nt * 16 + (lv & 15);
    const int kb = kc * 32 + ((lv >> 4) << 3);
#pragma unroll
    for (int j = 0; j < 8; ++j) {
        float v = Wg[(size_t)l * 16384 + (size_t)(kb + j) * WID + n];
        Bfrag[(size_t)e * 512 + lv * 8 + j] = rne_bf16(v);
    }
}

__device__ __forceinline__ unsigned int pack_bf2(float a, float b) {
    union { __hip_bfloat162 h2; unsigned int u; } cv;
    cv.h2 = __float22bfloat162_rn(make_float2(a, b));   // low16 = a (even col)
    return cv.u;
}

// ---------------------------------------------------------------------------
// Fused net (r9 structure, best measured 62us). Each wave owns 16 NODES
// (u = ublk+16w+(lane&15)) and computes TWO MFMA tiles per layer (batch b and
// b+2) -> graph pair-mix is register-local (zero shuffles). LDS round-trip
// for the B-fragment relayout; wave-private slices; no barriers.
// r12 change (register-REDUCING, r9 is pinned at the 124-VGPR/4-wave cliff):
// MFMA loop is kc-outer/nt-inner. X-fragments: 2 live (8 regs) instead of
// 8 (32 regs); acc dependent-chain distance 4 -> 16 MFMAs; freed regs let
// the scheduler keep several per-kc Bfrag L2 loads in flight under MFMAs.
// ---------------------------------------------------------------------------
__global__ __launch_bounds__(256) void fused_kernel(
    const float* __restrict__ u0, const float* __restrict__ P,
    const float* __restrict__ W_in, const float* __restrict__ b_in,
    const unsigned short* __restrict__ Bfrag,
    const float* __restrict__ bg, const float* __restrict__ gamma,
    const float* __restrict__ beta, const float* __restrict__ W_out,
    const float* __restrict__ b_out, float* __restrict__ out)
{
    __shared__ unsigned int XsH[8][16 * STRW];   // 34816 B

    const int tid  = threadIdx.x;
    const int w    = tid >> 6;
    const int lane = tid & 63;
    const int l15  = lane & 15;
    const int lhi  = lane >> 4;      // 0..3

    const int blk  = blockIdx.x;     // 0..1023
    const int b    = blk >> 9;       // 0 or 1; partner batch = b+2
    const int ublk = (blk & 511) << 6;

    const int u  = ublk + 16 * w + l15;
    const int ix = u >> 7;
    const int t  = u & 127;

    // degree coeffs (t-major graph indexing), per-lane
    float c1, c2;
    {
        int gi = u & 255, gt = u >> 8;
        int d  = (gi > 0) + (gi < 255) + (gt > 0) + (gt < 127);
        float deg = 2.f * (float)d + 1.f;
        c1 = 2.f * (float)d * rsqrtf(deg);
        c2 = 1.f / deg;
    }

    // ---- features of node u for batch b (A) and b+2 (B) ----
    float featA[7], featB[7];
    {
        float s  = ((float)t + 0.5f) * 0.125f - 0.5f;
        float fs = floorf(s);
        int   t0 = (int)fs;
        float wt = s - fs;
        int t0c = t0 < 0 ? 0 : (t0 > 15 ? 15 : t0);
        int t1n = t0 + 1;
        int t1c = t1n < 0 ? 0 : (t1n > 15 ? 15 : t1n);
        const float* urA = u0 + ((size_t)b * NXX + ix) * 16;
        const float* urB = u0 + ((size_t)(b + 2) * NXX + ix) * 16;
        featA[0] = urA[t0c] * (1.f - wt) + urA[t1c] * wt;
        featB[0] = urB[t0c] * (1.f - wt) + urB[t1c] * wt;
#pragma unroll
        for (int f = 0; f < 4; ++f) {
            featA[1 + f] = P[b * 4 + f];
            featB[1 + f] = P[(b + 2) * 4 + f];
        }
        featA[5] = featB[5] = (float)ix * (1.f / 255.f);
        featA[6] = featB[6] = (float)t  * (1.f / 127.f);
    }

    // ---- X0 = feat @ W_in + b_in for both tiles (shared W_in loads) ----
    float xr0[8][4], xr1[8][4];
#pragma unroll
    for (int nt = 0; nt < 8; ++nt) {
        const int c = nt * 16 + 4 * lhi;
        float4 bi4 = *(const float4*)(b_in + c);
        float4 wf[7];
#pragma unroll
        for (int f = 0; f < 7; ++f) wf[f] = *(const float4*)(W_in + f * WID + c);
#pragma unroll
        for (int r = 0; r < 4; ++r) {
            float a0 = ((const float*)&bi4)[r];
            float a1 = a0;
#pragma unroll
            for (int f = 0; f < 7; ++f) {
                float wv = ((const float*)&wf[f])[r];
                a0 = fmaf(featA[f], wv, a0);
                a1 = fmaf(featB[f], wv, a1);
            }
            xr0[nt][r] = a0;
            xr1[nt][r] = a1;
        }
    }

    unsigned int* Hrow0 = &XsH[2 * w][l15 * STRW];
    unsigned int* Hrow1 = &XsH[2 * w + 1][l15 * STRW];

    // ======== 4 GCN layers (barrier-free) ========
    for (int l = 0; l < 4; ++l) {
        // ---- pack bf16 and store both tiles (one b64 per nt per tile) ----
#pragma unroll
        for (int nt = 0; nt < 8; ++nt) {
            unsigned int p0 = pack_bf2(xr0[nt][0], xr0[nt][1]);
            unsigned int p1 = pack_bf2(xr0[nt][2], xr0[nt][3]);
            *(uint2*)(Hrow0 + 8 * nt + 2 * lhi) = make_uint2(p0, p1);
            unsigned int q0 = pack_bf2(xr1[nt][0], xr1[nt][1]);
            unsigned int q1 = pack_bf2(xr1[nt][2], xr1[nt][3]);
            *(uint2*)(Hrow1 + 8 * nt + 2 * lhi) = make_uint2(q0, q1);
        }

        // ---- MFMA: kc-outer / nt-inner (2 live X-frags, long acc chains) ----
        f32x4 acc0[8], acc1[8];
#pragma unroll
        for (int nt = 0; nt < 8; ++nt) {
            acc0[nt] = (f32x4){0.f, 0.f, 0.f, 0.f};
            acc1[nt] = (f32x4){0.f, 0.f, 0.f, 0.f};
        }
        const unsigned short* bp = Bfrag + (size_t)l * 16384 + lane * 8;
#pragma unroll
        for (int kc = 0; kc < 4; ++kc) {
            bf16x8 x0 = *(const bf16x8*)(Hrow0 + 16 * kc + 4 * lhi);
            bf16x8 x1 = *(const bf16x8*)(Hrow1 + 16 * kc + 4 * lhi);
#pragma unroll
            for (int nt = 0; nt < 8; ++nt) {
                bf16x8 bh = *(const bf16x8*)(bp + (kc * 8 + nt) * 512);
                acc0[nt] = __builtin_amdgcn_mfma_f32_16x16x32_bf16(bh, x0, acc0[nt], 0, 0, 0);
                acc1[nt] = __builtin_amdgcn_mfma_f32_16x16x32_bf16(bh, x1, acc1[nt], 0, 0, 0);
            }
        }

        // ---- epilogue: REGISTER-LOCAL pair mix, +bg, LN, residual ReLU ----
        float s0 = 0.f, q0 = 0.f, s1 = 0.f, q1 = 0.f;
#pragma unroll
        for (int nt = 0; nt < 8; ++nt) {
            float4 bg4 = *(const float4*)(bg + l * WID + nt * 16 + 4 * lhi);
#pragma unroll
            for (int r = 0; r < 4; ++r) {
                float bgr = ((const float*)&bg4)[r];
                float h0 = acc0[nt][r];
                float h1 = acc1[nt][r];
                float a0 = h0 + bgr;                          // batch b (deg 1)
                float a1 = fmaf(c1, h0, fmaf(c2, h1, bgr));   // batch b+2
                acc0[nt][r] = a0;
                acc1[nt][r] = a1;
                s0 += a0;  q0 = fmaf(a0, a0, q0);
                s1 += a1;  q1 = fmaf(a1, a1, q1);
            }
        }
        s0 += __shfl_xor(s0, 16);  q0 += __shfl_xor(q0, 16);
        s1 += __shfl_xor(s1, 16);  q1 += __shfl_xor(q1, 16);
        s0 += __shfl_xor(s0, 32);  q0 += __shfl_xor(q0, 32);
        s1 += __shfl_xor(s1, 32);  q1 += __shfl_xor(q1, 32);
        float mu0 = s0 * (1.f / 128.f);
        float mu1 = s1 * (1.f / 128.f);
        float rs0 = rsqrtf(q0 * (1.f / 128.f) - mu0 * mu0 + 1e-5f);
        float rs1 = rsqrtf(q1 * (1.f / 128.f) - mu1 * mu1 + 1e-5f);
#pragma unroll
        for (int nt = 0; nt < 8; ++nt) {
            const int c = nt * 16 + 4 * lhi;
            float4 g4 = *(const float4*)(gamma + l * WID + c);
            float4 e4 = *(const float4*)(beta  + l * WID + c);
#pragma unroll
            for (int r = 0; r < 4; ++r) {
                float gv = ((const float*)&g4)[r];
                float ev = ((const float*)&e4)[r];
                float n0 = fmaf((acc0[nt][r] - mu0) * rs0, gv, ev);
                float n1 = fmaf((acc1[nt][r] - mu1) * rs1, gv, ev);
                xr0[nt][r] = fmaxf(n0 + xr0[nt][r], 0.f);
                xr1[nt][r] = fmaxf(n1 + xr1[nt][r], 0.f);
            }
        }
        // no barrier: wave-private LDS slices; within-wave DS deps order them.
    }

    // ======== out head: two rows per lane ========
    float p0 = 0.f, p1 = 0.f;
#pragma unroll
    for (int nt = 0; nt < 8; ++nt) {
        float4 wo4 = *(const float4*)(W_out + nt * 16 + 4 * lhi);
#pragma unroll
        for (int r = 0; r < 4; ++r) {
            float wv = ((const float*)&wo4)[r];
            p0 = fmaf(xr0[nt][r], wv, p0);
            p1 = fmaf(xr1[nt][r], wv, p1);
        }
    }
    p0 += __shfl_xor(p0, 16);  p1 += __shfl_xor(p1, 16);
    p0 += __shfl_xor(p0, 32);  p1 += __shfl_xor(p1, 32);
    if (lhi == 0) {
        float bo = b_out[0];
        out[(size_t)b * NG + u]       = p0 + bo;
        out[(size_t)(b + 2) * NG + u] = p1 + bo;
    }
}

// ---------------------------------------------------------------------------
extern "C" void kernel_launch(void* const* d_in, const int* in_sizes, int n_in,
                              void* d_out, int out_size, void* d_ws, size_t ws_size,
                              hipStream_t stream) {
    const float* u0    = (const float*)d_in[0];
    const float* P     = (const float*)d_in[1];
    const float* W_in  = (const float*)d_in[2];
    const float* b_in  = (const float*)d_in[3];
    const float* Wg    = (const float*)d_in[4];
    const float* bg    = (const float*)d_in[5];
    const float* gamma = (const float*)d_in[6];
    const float* beta  = (const float*)d_in[7];
    const float* W_out = (const float*)d_in[8];
    const float* b_out = (const float*)d_in[9];

    unsigned short* Bfrag = (unsigned short*)d_ws;   // 128 KB

    prep_kernel<<<128, 64, 0, stream>>>(Wg, Bfrag);
    fused_kernel<<<1024, 256, 0, stream>>>(
        u0, P, W_in, b_in, Bfrag, bg, gamma, beta, W_out, b_out, (float*)d_out);
}

// Round 13
// 55.221 us; speedup vs baseline: 1.8624x; 1.1300x over previous
//
#include <hip/hip_runtime.h>
#include <hip/hip_bf16.h>

#define NXX 256
#define NG 32768
#define WID 128

typedef short bf16x8 __attribute__((ext_vector_type(8)));
typedef float f32x4 __attribute__((ext_vector_type(4)));
typedef unsigned int u32x4 __attribute__((ext_vector_type(4)));

__device__ __forceinline__ unsigned short rne_bf16(float x) {
    unsigned int u = __float_as_uint(x);
    return (unsigned short)((u + 0x7fffu + ((u >> 16) & 1u)) >> 16);
}

// ---------------------------------------------------------------------------
// Prep (pi version, r7-hardware-verified): pack Wg into A-operand fragment
// streams with the k-axis PRE-PERMUTED by
//   pi: k=(kc:2|g:2|j2:1|j10:2) -> ch=(kc:2|j2:1|g:2|j10:2).
// GEMM is invariant under a common k-permutation of W and x; pi makes the
// B-fragment for k-chunk kc equal to a direct cvt_pk packing of the thread's
// own D registers xres[2kc..2kc+1][0..3] -> NO X LDS round trip.
// Lane lv elem j of stream e=(l*4+kc)*8+nt holds W[pi(kc,g,j)][16nt+(lv&15)].
// ---------------------------------------------------------------------------
__global__ __launch_bounds__(64) void prep_kernel(
    const float* __restrict__ Wg, unsigned short* __restrict__ Bfrag) {
    const int e  = blockIdx.x;       // 0..127
    const int lv = threadIdx.x;      // 0..63
    const int l  = e >> 5;
    const int kc = (e >> 3) & 3;
    const int nt = e & 7;
    const int n  = nt * 16 + (lv & 15);
    const int g  = lv >> 4;          // k-granule 0..3
#pragma unroll
    for (int j = 0; j < 8; ++j) {
        const int ch = kc * 32 + ((j >> 2) << 4) + (g << 2) + (j & 3);  // pi
        float v = Wg[(size_t)l * 16384 + (size_t)ch * WID + n];
        Bfrag[(size_t)e * 512 + lv * 8 + j] = rne_bf16(v);
    }
}

__device__ __forceinline__ unsigned int pack_bf2(float a, float b) {
    union { __hip_bfloat162 h2; unsigned int u; } cv;
    cv.h2 = __float22bfloat162_rn(make_float2(a, b));   // low16 = a
    return cv.u;
}

union fragu { bf16x8 f; u32x4 u; };

// ---------------------------------------------------------------------------
// Fused net (r12 structure minus the X-LDS round trip). Each wave owns 16
// NODES (u = ublk+16w+(lane&15)), computes TWO MFMA tiles per layer (batch b
// and b+2) -> pair-mix register-local. kc-outer/nt-inner MFMA loop.
// B-fragments built per-kc by 8 cvt_pk straight from xres registers (pi
// layout) — zero LDS, zero barriers, no staging arrays (register-neutral;
// r10/r11 showed the 128-VGPR cliff kills anything register-positive).
// ---------------------------------------------------------------------------
__global__ __launch_bounds__(256) void fused_kernel(
    const float* __restrict__ u0, const float* __restrict__ P,
    const float* __restrict__ W_in, const float* __restrict__ b_in,
    const unsigned short* __restrict__ Bfrag,
    const float* __restrict__ bg, const float* __restrict__ gamma,
    const float* __restrict__ beta, const float* __restrict__ W_out,
    const float* __restrict__ b_out, float* __restrict__ out)
{
    const int tid  = threadIdx.x;
    const int w    = tid >> 6;
    const int lane = tid & 63;
    const int l15  = lane & 15;
    const int lhi  = lane >> 4;      // 0..3

    const int blk  = blockIdx.x;     // 0..1023
    const int b    = blk >> 9;       // 0 or 1; partner batch = b+2
    const int ublk = (blk & 511) << 6;

    const int u  = ublk + 16 * w + l15;
    const int ix = u >> 7;
    const int t  = u & 127;

    // degree coeffs (t-major graph indexing), per-lane
    float c1, c2;
    {
        int gi = u & 255, gt = u >> 8;
        int d  = (gi > 0) + (gi < 255) + (gt > 0) + (gt < 127);
        float deg = 2.f * (float)d + 1.f;
        c1 = 2.f * (float)d * rsqrtf(deg);
        c2 = 1.f / deg;
    }

    // ---- features of node u for batch b (A) and b+2 (B) ----
    float featA[7], featB[7];
    {
        float s  = ((float)t + 0.5f) * 0.125f - 0.5f;
        float fs = floorf(s);
        int   t0 = (int)fs;
        float wt = s - fs;
        int t0c = t0 < 0 ? 0 : (t0 > 15 ? 15 : t0);
        int t1n = t0 + 1;
        int t1c = t1n < 0 ? 0 : (t1n > 15 ? 15 : t1n);
        const float* urA = u0 + ((size_t)b * NXX + ix) * 16;
        const float* urB = u0 + ((size_t)(b + 2) * NXX + ix) * 16;
        featA[0] = urA[t0c] * (1.f - wt) + urA[t1c] * wt;
        featB[0] = urB[t0c] * (1.f - wt) + urB[t1c] * wt;
#pragma unroll
        for (int f = 0; f < 4; ++f) {
            featA[1 + f] = P[b * 4 + f];
            featB[1 + f] = P[(b + 2) * 4 + f];
        }
        featA[5] = featB[5] = (float)ix * (1.f / 255.f);
        featA[6] = featB[6] = (float)t  * (1.f / 127.f);
    }

    // ---- X0 = feat @ W_in + b_in for both tiles (shared W_in loads) ----
    float xr0[8][4], xr1[8][4];
#pragma unroll
    for (int nt = 0; nt < 8; ++nt) {
        const int c = nt * 16 + 4 * lhi;
        float4 bi4 = *(const float4*)(b_in + c);
        float4 wf[7];
#pragma unroll
        for (int f = 0; f < 7; ++f) wf[f] = *(const float4*)(W_in + f * WID + c);
#pragma unroll
        for (int r = 0; r < 4; ++r) {
            float a0 = ((const float*)&bi4)[r];
            float a1 = a0;
#pragma unroll
            for (int f = 0; f < 7; ++f) {
                float wv = ((const float*)&wf[f])[r];
                a0 = fmaf(featA[f], wv, a0);
                a1 = fmaf(featB[f], wv, a1);
            }
            xr0[nt][r] = a0;
            xr1[nt][r] = a1;
        }
    }

    // ======== 4 GCN layers (no LDS, no barriers) ========
    for (int l = 0; l < 4; ++l) {
        // ---- MFMA: kc-outer / nt-inner; fragments packed per-kc from regs --
        f32x4 acc0[8], acc1[8];
#pragma unroll
        for (int nt = 0; nt < 8; ++nt) {
            acc0[nt] = (f32x4){0.f, 0.f, 0.f, 0.f};
            acc1[nt] = (f32x4){0.f, 0.f, 0.f, 0.f};
        }
        const unsigned short* bp = Bfrag + (size_t)l * 16384 + lane * 8;
#pragma unroll
        for (int kc = 0; kc < 4; ++kc) {
            fragu x0f, x1f;
            x0f.u = (u32x4){pack_bf2(xr0[2 * kc][0],     xr0[2 * kc][1]),
                            pack_bf2(xr0[2 * kc][2],     xr0[2 * kc][3]),
                            pack_bf2(xr0[2 * kc + 1][0], xr0[2 * kc + 1][1]),
                            pack_bf2(xr0[2 * kc + 1][2], xr0[2 * kc + 1][3])};
            x1f.u = (u32x4){pack_bf2(xr1[2 * kc][0],     xr1[2 * kc][1]),
                            pack_bf2(xr1[2 * kc][2],     xr1[2 * kc][3]),
                            pack_bf2(xr1[2 * kc + 1][0], xr1[2 * kc + 1][1]),
                            pack_bf2(xr1[2 * kc + 1][2], xr1[2 * kc + 1][3])};
#pragma unroll
            for (int nt = 0; nt < 8; ++nt) {
                bf16x8 bh = *(const bf16x8*)(bp + (kc * 8 + nt) * 512);
                acc0[nt] = __builtin_amdgcn_mfma_f32_16x16x32_bf16(bh, x0f.f, acc0[nt], 0, 0, 0);
                acc1[nt] = __builtin_amdgcn_mfma_f32_16x16x32_bf16(bh, x1f.f, acc1[nt], 0, 0, 0);
            }
        }

        // ---- epilogue: REGISTER-LOCAL pair mix, +bg, LN, residual ReLU ----
        float s0 = 0.f, q0 = 0.f, s1 = 0.f, q1 = 0.f;
#pragma unroll
        for (int nt = 0; nt < 8; ++nt) {
            float4 bg4 = *(const float4*)(bg + l * WID + nt * 16 + 4 * lhi);
#pragma unroll
            for (int r = 0; r < 4; ++r) {
                float bgr = ((const float*)&bg4)[r];
                float h0 = acc0[nt][r];
                float h1 = acc1[nt][r];
                float a0 = h0 + bgr;                          // batch b (deg 1)
                float a1 = fmaf(c1, h0, fmaf(c2, h1, bgr));   // batch b+2
                acc0[nt][r] = a0;
                acc1[nt][r] = a1;
                s0 += a0;  q0 = fmaf(a0, a0, q0);
                s1 += a1;  q1 = fmaf(a1, a1, q1);
            }
        }
        s0 += __shfl_xor(s0, 16);  q0 += __shfl_xor(q0, 16);
        s1 += __shfl_xor(s1, 16);  q1 += __shfl_xor(q1, 16);
        s0 += __shfl_xor(s0, 32);  q0 += __shfl_xor(q0, 32);
        s1 += __shfl_xor(s1, 32);  q1 += __shfl_xor(q1, 32);
        float mu0 = s0 * (1.f / 128.f);
        float mu1 = s1 * (1.f / 128.f);
        float rs0 = rsqrtf(q0 * (1.f / 128.f) - mu0 * mu0 + 1e-5f);
        float rs1 = rsqrtf(q1 * (1.f / 128.f) - mu1 * mu1 + 1e-5f);
#pragma unroll
        for (int nt = 0; nt < 8; ++nt) {
            const int c = nt * 16 + 4 * lhi;
            float4 g4 = *(const float4*)(gamma + l * WID + c);
            float4 e4 = *(const float4*)(beta  + l * WID + c);
#pragma unroll
            for (int r = 0; r < 4; ++r) {
                float gv = ((const float*)&g4)[r];
                float ev = ((const float*)&e4)[r];
                float n0 = fmaf((acc0[nt][r] - mu0) * rs0, gv, ev);
                float n1 = fmaf((acc1[nt][r] - mu1) * rs1, gv, ev);
                xr0[nt][r] = fmaxf(n0 + xr0[nt][r], 0.f);
                xr1[nt][r] = fmaxf(n1 + xr1[nt][r], 0.f);
            }
        }
    }

    // ======== out head: two rows per lane ========
    float p0 = 0.f, p1 = 0.f;
#pragma unroll
    for (int nt = 0; nt < 8; ++nt) {
        float4 wo4 = *(const float4*)(W_out + nt * 16 + 4 * lhi);
#pragma unroll
        for (int r = 0; r < 4; ++r) {
            float wv = ((const float*)&wo4)[r];
            p0 = fmaf(xr0[nt][r], wv, p0);
            p1 = fmaf(xr1[nt][r], wv, p1);
        }
    }
    p0 += __shfl_xor(p0, 16);  p1 += __shfl_xor(p1, 16);
    p0 += __shfl_xor(p0, 32);  p1 += __shfl_xor(p1, 32);
    if (lhi == 0) {
        float bo = b_out[0];
        out[(size_t)b * NG + u]       = p0 + bo;
        out[(size_t)(b + 2) * NG + u] = p1 + bo;
    }
}

// ---------------------------------------------------------------------------
extern "C" void kernel_launch(void* const* d_in, const int* in_sizes, int n_in,
                              void* d_out, int out_size, void* d_ws, size_t ws_size,
                              hipStream_t stream) {
    const float* u0    = (const float*)d_in[0];
    const float* P     = (const float*)d_in[1];
    const float* W_in  = (const float*)d_in[2];
    const float* b_in  = (const float*)d_in[3];
    const float* Wg    = (const float*)d_in[4];
    const float* bg    = (const float*)d_in[5];
    const float* gamma = (const float*)d_in[6];
    const float* beta  = (const float*)d_in[7];
    const float* W_out = (const float*)d_in[8];
    const float* b_out = (const float*)d_in[9];

    unsigned short* Bfrag = (unsigned short*)d_ws;   // 128 KB

    prep_kernel<<<128, 64, 0, stream>>>(Wg, Bfrag);
    fused_kernel<<<1024, 256, 0, stream>>>(
        u0, P, W_in, b_in, Bfrag, bg, gamma, beta, W_out, b_out, (float*)d_out);
}